// Round 11
// baseline (258.889 us; speedup 1.0000x reference)
//
#include <hip/hip_runtime.h>

// NodeFeatures: out = relu(x@Wu^T + bu + mask @ (x@Wv^T + bv))
// B=8, N=2048, D=128.
// R10: k2 89us, MfmaUtil 3.5%, HBM 11%, conflicts ~1% (non-issue). Limiter =
// __syncthreads vmcnt(0) drain each K-step (DMA issued ~200cy before drain).
// R11 (T3/T4 port): 4-buffer LDS, DMA at distance-2 iters, V regs ping-pong
// (named Va/Vb, unroll-2 body, rule #20), per-iter counted wait
// "s_waitcnt vmcnt(18)" + raw s_barrier + sched_barrier(0) (rule #18).
// Never vmcnt(0) in loop. 4-buf WAR analysis: buf[(t+2)&3] last read at
// compute(t-2) < barrier#(t-1) for all waves -> safe (3-buf would race).

typedef __bf16 bf16x8 __attribute__((ext_vector_type(8)));
typedef __bf16 bf16x4 __attribute__((ext_vector_type(4)));
typedef float  f32x4  __attribute__((ext_vector_type(4)));

#define MFMA16(A, B, C) __builtin_amdgcn_mfma_f32_16x16x32_bf16(A, B, C, 0, 0, 0)

static __device__ __forceinline__ bf16x8 cvt8(const float* __restrict__ p) {
    float4 a = *(const float4*)p;
    float4 b = *(const float4*)(p + 4);
    bf16x8 v;
    v[0] = (__bf16)a.x; v[1] = (__bf16)a.y; v[2] = (__bf16)a.z; v[3] = (__bf16)a.w;
    v[4] = (__bf16)b.x; v[5] = (__bf16)b.y; v[6] = (__bf16)b.z; v[7] = (__bf16)b.w;
    return v;
}

static __device__ __forceinline__ bf16x8 pack8(const float4 a, const float4 b) {
    bf16x8 v;
    v[0] = (__bf16)a.x; v[1] = (__bf16)a.y; v[2] = (__bf16)a.z; v[3] = (__bf16)a.w;
    v[4] = (__bf16)b.x; v[5] = (__bf16)b.y; v[6] = (__bf16)b.z; v[7] = (__bf16)b.w;
    return v;
}

static __device__ __forceinline__ void gload_lds16(const float* g, float* l) {
    __builtin_amdgcn_global_load_lds(
        (const __attribute__((address_space(1))) void*)g,
        (__attribute__((address_space(3))) void*)l, 16, 0, 0);
}

// ---------------------------------------------------------------------------
// Kernel 1 (unchanged): Uxb = bf16(x@Wu^T+bu); Vt[b][e][n] = bf16(x@Wv^T+bv)
// D-frag (m89-verified): col = lane&15, row = (lane>>4)*4 + reg.
// ---------------------------------------------------------------------------
__global__ __launch_bounds__(256) void k1_uv(
    const float* __restrict__ x,  const float* __restrict__ Wu,
    const float* __restrict__ bu, const float* __restrict__ Wv,
    const float* __restrict__ bv,
    __bf16* __restrict__ Uxb, __bf16* __restrict__ Vt)
{
    const int tid  = threadIdx.x;
    const int wv   = tid >> 6;
    const int lane = tid & 63;
    const int l16  = lane & 15;
    const int l4   = lane >> 4;
    const int row0 = blockIdx.x * 64;
    const int e0   = wv * 32;

    const f32x4 zero = {0.f, 0.f, 0.f, 0.f};
    f32x4 acc[4][4];
    #pragma unroll
    for (int mt = 0; mt < 4; ++mt)
        #pragma unroll
        for (int f = 0; f < 4; ++f) acc[mt][f] = zero;

    #pragma unroll
    for (int kf = 0; kf < 4; ++kf) {
        const int ko = kf * 32 + l4 * 8;
        bf16x8 af[4], bf[4];
        #pragma unroll
        for (int mt = 0; mt < 4; ++mt)
            af[mt] = cvt8(x + (size_t)(row0 + mt * 16 + l16) * 128 + ko);
        bf[0] = cvt8(Wu + (size_t)(e0 +      l16) * 128 + ko);
        bf[1] = cvt8(Wu + (size_t)(e0 + 16 + l16) * 128 + ko);
        bf[2] = cvt8(Wv + (size_t)(e0 +      l16) * 128 + ko);
        bf[3] = cvt8(Wv + (size_t)(e0 + 16 + l16) * 128 + ko);
        #pragma unroll
        for (int mt = 0; mt < 4; ++mt)
            #pragma unroll
            for (int f = 0; f < 4; ++f)
                acc[mt][f] = MFMA16(af[mt], bf[f], acc[mt][f]);
    }

    const int bidx = row0 >> 11;
    #pragma unroll
    for (int f = 0; f < 4; ++f) {
        const int e    = e0 + (f & 1) * 16 + l16;
        const bool isV = (f >= 2);
        const float bias = isV ? bv[e] : bu[e];
        #pragma unroll
        for (int mt = 0; mt < 4; ++mt) {
            if (!isV) {
                #pragma unroll
                for (int r = 0; r < 4; ++r) {
                    const int row = row0 + mt * 16 + l4 * 4 + r;
                    Uxb[(size_t)row * 128 + e] = (__bf16)(acc[mt][f][r] + bias);
                }
            } else {
                const int nbase = (row0 & 2047) + mt * 16 + l4 * 4;
                bf16x4 pk;
                #pragma unroll
                for (int r = 0; r < 4; ++r) pk[r] = (__bf16)(acc[mt][f][r] + bias);
                *(bf16x4*)(Vt + ((size_t)bidx * 128 + e) * 2048 + nbase) = pk;
            }
        }
    }
}

// ---------------------------------------------------------------------------
// Kernel 2 (R11): BM=16, BK=128, 16 K-steps, counted-vmcnt pipeline.
// Per iter t: STAGE(t+2) [2 DMA] ; LOADV(t+1) [8 global] ;
//   s_waitcnt vmcnt(18)  (retires ONLY the 1-iter-old DMA pair) ;
//   s_barrier ; sched_barrier ; COMPUTE(t) (compiler waits V(t) via counted
//   vmcnt(10), LDS reads via lgkmcnt). Grid 1024 (XCD-swizzled), 4 blk/CU.
// ---------------------------------------------------------------------------
__global__ __launch_bounds__(256) void k2_agg(
    const float* __restrict__ mask,
    const __bf16* __restrict__ Vt,
    const __bf16* __restrict__ Uxb,
    float* __restrict__ out)
{
    __shared__ float smem[4][16 * 128];   // 4 x 8KB f32 mask tiles, swizzled

    const int bid = blockIdx.x;                    // 0..1023
    const int lb  = (bid & 7) * 128 + (bid >> 3);  // bijective XCD swizzle (1024=8*128)
    const int b   = lb >> 7;                       // batch (one batch per XCD)
    const int m0  = (lb & 127) * 16;               // row tile within batch

    const int tid  = threadIdx.x;
    const int wv   = tid >> 6;
    const int lane = tid & 63;
    const int l16  = lane & 15;
    const int l4   = lane >> 4;

    // DMA staging: LDS dest linear (base + lane*16B); global source
    // pre-swizzled at 16B-chunk granularity: LDS chunk c of row r holds
    // global chunk c ^ (r&7). DMA0 -> rows wv*4+{0,1}, DMA1 -> +{2,3}.
    const int r_i0 = wv * 4 + (lane >> 5);
    const int r_i1 = r_i0 + 2;
    const int s4   = lane & 31;
    const float* g0 = mask + ((size_t)b * 2048 + m0 + r_i0) * 2048
                           + (s4 ^ (r_i0 & 7)) * 4;
    const float* g1 = mask + ((size_t)b * 2048 + m0 + r_i1) * 2048
                           + (s4 ^ (r_i1 & 7)) * 4;

    // B operand base (Vt is [128e][2048n] per batch, L2-hot within the XCD)
    const __bf16* vb = Vt + ((size_t)b * 128 + wv * 32 + l16) * 2048 + l4 * 8;

    f32x4 acc[2];
    acc[0] = {0.f, 0.f, 0.f, 0.f};
    acc[1] = {0.f, 0.f, 0.f, 0.f};

#define STAGE(BUF, KS) {                                                      \
    gload_lds16(g0 + (size_t)(KS) * 128, &smem[BUF][wv * 512]);               \
    gload_lds16(g1 + (size_t)(KS) * 128, &smem[BUF][wv * 512 + 256]); }

#define LOADV(V, KS) {                                                        \
    const __bf16* q = vb + (size_t)(KS) * 128;                                \
    V[0] = *(const bf16x8*)(q);                                               \
    V[1] = *(const bf16x8*)(q + (size_t)16 * 2048);                           \
    V[2] = *(const bf16x8*)(q + 32);                                          \
    V[3] = *(const bf16x8*)(q + (size_t)16 * 2048 + 32);                      \
    V[4] = *(const bf16x8*)(q + 64);                                          \
    V[5] = *(const bf16x8*)(q + (size_t)16 * 2048 + 64);                      \
    V[6] = *(const bf16x8*)(q + 96);                                          \
    V[7] = *(const bf16x8*)(q + (size_t)16 * 2048 + 96); }

#define WAITPUB() {                                                           \
    asm volatile("s_waitcnt vmcnt(18)" ::: "memory");                         \
    __builtin_amdgcn_s_barrier();                                             \
    __builtin_amdgcn_sched_barrier(0); }

#define COMPUTE(BUF, V) {                                                     \
    _Pragma("unroll")                                                         \
    for (int kf = 0; kf < 4; ++kf) {                                          \
        const int q2 = (kf * 4 + l4) * 2;                                     \
        const int p0 = (q2       ^ (l16 & 7)) * 4;                            \
        const int p1 = ((q2 + 1) ^ (l16 & 7)) * 4;                            \
        bf16x8 af = pack8(*(const float4*)&smem[BUF][l16 * 128 + p0],         \
                          *(const float4*)&smem[BUF][l16 * 128 + p1]);        \
        acc[0] = MFMA16(af, V[kf * 2],     acc[0]);                           \
        acc[1] = MFMA16(af, V[kf * 2 + 1], acc[1]);                           \
    } }

    bf16x8 Va[8], Vb[8];

    // Prologue: D0->buf0, D1->buf1, V(0)->Va; retire D0 (vmcnt(10)); publish.
    STAGE(0, 0)
    STAGE(1, 1)
    LOADV(Va, 0)
    asm volatile("s_waitcnt vmcnt(10)" ::: "memory");
    __builtin_amdgcn_s_barrier();
    __builtin_amdgcn_sched_barrier(0);

    // 16 K-steps as 8 unroll-2 iterations (named V sets, rule #20).
    // Clamped tail indices re-stage/re-load tile 15 (unused, harmless, keeps
    // the vmcnt arithmetic uniform).
    for (int u = 0; u < 8; ++u) {
        const int t = 2 * u;
        const int sA = t + 2;                       // <= 16
        const int sB = t + 3;                       // <= 17
        const int tsA = sA < 16 ? sA : 15;
        const int tsB = sB < 16 ? sB : 15;
        const int tvA = t + 1;                      // <= 15 always
        const int tvB = sA < 16 ? sA : 15;          // V for t+2, clamped

        // t even: compute buf[t&3] with Va
        STAGE((sA & 3), tsA)
        LOADV(Vb, tvA)
        WAITPUB()
        COMPUTE((t & 3), Va)

        // t+1 odd: compute buf[(t+1)&3] with Vb
        STAGE((sB & 3), tsB)
        LOADV(Va, tvB)
        WAITPUB()
        COMPUTE(((t + 1) & 3), Vb)
    }
#undef STAGE
#undef LOADV
#undef WAITPUB
#undef COMPUTE

    // epilogue: out = relu(acc + Ux); D-frag: col=l16, row=l4*4+reg
    const size_t rowbase = (size_t)b * 2048 + m0;
    #pragma unroll
    for (int nf = 0; nf < 2; ++nf) {
        const int e = wv * 32 + nf * 16 + l16;
        #pragma unroll
        for (int r = 0; r < 4; ++r) {
            const size_t row = rowbase + l4 * 4 + r;
            const float v = acc[nf][r] + (float)Uxb[row * 128 + e];
            out[row * 128 + e] = v > 0.f ? v : 0.f;
        }
    }
}

// ---------------------------------------------------------------------------
extern "C" void kernel_launch(void* const* d_in, const int* in_sizes, int n_in,
                              void* d_out, int out_size, void* d_ws, size_t ws_size,
                              hipStream_t stream) {
    (void)in_sizes; (void)n_in; (void)out_size; (void)ws_size;
    const float* x    = (const float*)d_in[0];   // [8][2048][128]
    const float* mask = (const float*)d_in[1];   // [8][2048][2048]
    const float* Wu   = (const float*)d_in[2];   // [128][128]
    const float* bu   = (const float*)d_in[3];   // [128]
    const float* Wv   = (const float*)d_in[4];   // [128][128]
    const float* bv   = (const float*)d_in[5];   // [128]
    float* out        = (float*)d_out;           // [8][2048][128] f32

    __bf16* Vt  = (__bf16*)d_ws;                 // [8][128][2048] bf16 (4MB)
    __bf16* Uxb = Vt + (size_t)8 * 128 * 2048;   // [16384][128]  bf16 (4MB)

    hipLaunchKernelGGL(k1_uv, dim3(256), dim3(256), 0, stream, x, Wu, bu, Wv, bv, Uxb, Vt);
    hipLaunchKernelGGL(k2_agg, dim3(1024), dim3(256), 0, stream, mask, Vt, Uxb, out);
}

// Round 12
// 240.855 us; speedup vs baseline: 1.0749x; 1.0749x over previous
//
#include <hip/hip_runtime.h>

// NodeFeatures: out = relu(x@Wu^T + bu + mask @ (x@Wv^T + bv))
// B=8, N=2048, D=128.
// R10/R11 post-mortem: all sync variants stuck at 89-112us, MfmaUtil ~3%.
// Root cause (arithmetic, not sync): BM=16 => every block reads ALL of
// Vt[b] (512KB) => 512MB Vt traffic via L3 (~6.7Kcy/step/CU) vs mask 134MB.
// R12: BM=64, 8 waves, grid 256 (1 blk/CU): Vt -> 128MB; wave = 16-col
// n-slice (V loads disjoint, 4/wave/step); mask 64x128 f32 tile DMA-staged
// to LDS once, shared by all 8 waves; 16 MFMA per wave-step (2:1 MFMA:vmem).
// Pacing: HBM 3.2Kcy || LDS 3.4Kcy per step -> ~23us target.

typedef __bf16 bf16x8 __attribute__((ext_vector_type(8)));
typedef __bf16 bf16x4 __attribute__((ext_vector_type(4)));
typedef float  f32x4  __attribute__((ext_vector_type(4)));

#define MFMA16(A, B, C) __builtin_amdgcn_mfma_f32_16x16x32_bf16(A, B, C, 0, 0, 0)

static __device__ __forceinline__ bf16x8 cvt8(const float* __restrict__ p) {
    float4 a = *(const float4*)p;
    float4 b = *(const float4*)(p + 4);
    bf16x8 v;
    v[0] = (__bf16)a.x; v[1] = (__bf16)a.y; v[2] = (__bf16)a.z; v[3] = (__bf16)a.w;
    v[4] = (__bf16)b.x; v[5] = (__bf16)b.y; v[6] = (__bf16)b.z; v[7] = (__bf16)b.w;
    return v;
}

static __device__ __forceinline__ bf16x8 pack8(const float4 a, const float4 b) {
    bf16x8 v;
    v[0] = (__bf16)a.x; v[1] = (__bf16)a.y; v[2] = (__bf16)a.z; v[3] = (__bf16)a.w;
    v[4] = (__bf16)b.x; v[5] = (__bf16)b.y; v[6] = (__bf16)b.z; v[7] = (__bf16)b.w;
    return v;
}

static __device__ __forceinline__ void gload_lds16(const float* g, float* l) {
    __builtin_amdgcn_global_load_lds(
        (const __attribute__((address_space(1))) void*)g,
        (__attribute__((address_space(3))) void*)l, 16, 0, 0);
}

// ---------------------------------------------------------------------------
// Kernel 1 (unchanged): Uxb = bf16(x@Wu^T+bu); Vt[b][e][n] = bf16(x@Wv^T+bv)
// D-frag (m89-verified): col = lane&15, row = (lane>>4)*4 + reg.
// ---------------------------------------------------------------------------
__global__ __launch_bounds__(256) void k1_uv(
    const float* __restrict__ x,  const float* __restrict__ Wu,
    const float* __restrict__ bu, const float* __restrict__ Wv,
    const float* __restrict__ bv,
    __bf16* __restrict__ Uxb, __bf16* __restrict__ Vt)
{
    const int tid  = threadIdx.x;
    const int wv   = tid >> 6;
    const int lane = tid & 63;
    const int l16  = lane & 15;
    const int l4   = lane >> 4;
    const int row0 = blockIdx.x * 64;
    const int e0   = wv * 32;

    const f32x4 zero = {0.f, 0.f, 0.f, 0.f};
    f32x4 acc[4][4];
    #pragma unroll
    for (int mt = 0; mt < 4; ++mt)
        #pragma unroll
        for (int f = 0; f < 4; ++f) acc[mt][f] = zero;

    #pragma unroll
    for (int kf = 0; kf < 4; ++kf) {
        const int ko = kf * 32 + l4 * 8;
        bf16x8 af[4], bf[4];
        #pragma unroll
        for (int mt = 0; mt < 4; ++mt)
            af[mt] = cvt8(x + (size_t)(row0 + mt * 16 + l16) * 128 + ko);
        bf[0] = cvt8(Wu + (size_t)(e0 +      l16) * 128 + ko);
        bf[1] = cvt8(Wu + (size_t)(e0 + 16 + l16) * 128 + ko);
        bf[2] = cvt8(Wv + (size_t)(e0 +      l16) * 128 + ko);
        bf[3] = cvt8(Wv + (size_t)(e0 + 16 + l16) * 128 + ko);
        #pragma unroll
        for (int mt = 0; mt < 4; ++mt)
            #pragma unroll
            for (int f = 0; f < 4; ++f)
                acc[mt][f] = MFMA16(af[mt], bf[f], acc[mt][f]);
    }

    const int bidx = row0 >> 11;
    #pragma unroll
    for (int f = 0; f < 4; ++f) {
        const int e    = e0 + (f & 1) * 16 + l16;
        const bool isV = (f >= 2);
        const float bias = isV ? bv[e] : bu[e];
        #pragma unroll
        for (int mt = 0; mt < 4; ++mt) {
            if (!isV) {
                #pragma unroll
                for (int r = 0; r < 4; ++r) {
                    const int row = row0 + mt * 16 + l4 * 4 + r;
                    Uxb[(size_t)row * 128 + e] = (__bf16)(acc[mt][f][r] + bias);
                }
            } else {
                const int nbase = (row0 & 2047) + mt * 16 + l4 * 4;
                bf16x4 pk;
                #pragma unroll
                for (int r = 0; r < 4; ++r) pk[r] = (__bf16)(acc[mt][f][r] + bias);
                *(bf16x4*)(Vt + ((size_t)bidx * 128 + e) * 2048 + nbase) = pk;
            }
        }
    }
}

// ---------------------------------------------------------------------------
// Kernel 2 (R12): BM=64, BK=128, 16 K-steps, 8 waves (512 thr), grid 256.
// Wave wv owns output cols [wv*16, wv*16+16) x all 64 rows: per step
// 4 m-frags x 4 k-frags = 16 MFMA, 4 V-loads (disjoint cols, L2), A from
// shared LDS mask tile (DMA-staged f32, 16B-chunk XOR swizzle c^=(r&7)).
// Double-buffered 2x32KB LDS; STAGE(t+1) issued first, then V, then compute
// (covers DMA latency), then __syncthreads.
// ---------------------------------------------------------------------------
__global__ __launch_bounds__(512) void k2_agg(
    const float* __restrict__ mask,
    const __bf16* __restrict__ Vt,
    const __bf16* __restrict__ Uxb,
    float* __restrict__ out)
{
    __shared__ float smem[2][64 * 128];   // 2 x 32KB f32 mask tile, swizzled

    const int bid = blockIdx.x;                   // 0..255
    const int lb  = (bid & 7) * 32 + (bid >> 3);  // bijective XCD swizzle (256=8*32)
    const int b   = lb >> 5;                      // batch (one batch per XCD)
    const int m0  = (lb & 31) * 64;               // row tile within batch

    const int tid  = threadIdx.x;
    const int wv   = tid >> 6;                    // 0..7
    const int lane = tid & 63;
    const int l16  = lane & 15;
    const int l4   = lane >> 4;

    // DMA staging: wave wv stages rows wv*8..wv*8+7; instr d covers rows
    // wv*8+d*2+(lane>>5), 16B chunk lane&31. LDS dest linear (base+lane*16B);
    // global source pre-swizzled: LDS chunk c of row r holds global c^(r&7).
    const int rr   = (lane >> 5);                 // 0..1
    const int s4   = lane & 31;                   // 16B chunk in row
    const float* gsrc[4];
    int ldst[4];
    #pragma unroll
    for (int d = 0; d < 4; ++d) {
        const int r = wv * 8 + d * 2 + rr;        // 0..63
        gsrc[d] = mask + ((size_t)b * 2048 + m0 + r) * 2048 + (s4 ^ (r & 7)) * 4;
        ldst[d] = (wv * 8 + d * 2) * 128;         // wave-uniform float offset
    }

    // V operand base: wave's col e = wv*16 + l16; Vt[b][e][k], k base l4*8
    const __bf16* vb = Vt + ((size_t)b * 128 + wv * 16 + l16) * 2048 + l4 * 8;

    f32x4 acc[4];
    #pragma unroll
    for (int mt = 0; mt < 4; ++mt) acc[mt] = {0.f, 0.f, 0.f, 0.f};

#define STAGE(BUF, KS) {                                                      \
    gload_lds16(gsrc[0] + (size_t)(KS) * 128, &smem[BUF][ldst[0]]);           \
    gload_lds16(gsrc[1] + (size_t)(KS) * 128, &smem[BUF][ldst[1]]);           \
    gload_lds16(gsrc[2] + (size_t)(KS) * 128, &smem[BUF][ldst[2]]);           \
    gload_lds16(gsrc[3] + (size_t)(KS) * 128, &smem[BUF][ldst[3]]); }

    STAGE(0, 0)
    __syncthreads();

    for (int ks = 0; ks < 16; ++ks) {
        const int cur = ks & 1;
        if (ks + 1 < 16) STAGE(cur ^ 1, ks + 1)   // issue early: hides under compute
        // V fragments for this step (4 x bf16x8, L2-hot, disjoint per wave)
        bf16x8 V0 = *(const bf16x8*)(vb + (size_t)ks * 128);
        bf16x8 V1 = *(const bf16x8*)(vb + (size_t)ks * 128 + 32);
        bf16x8 V2 = *(const bf16x8*)(vb + (size_t)ks * 128 + 64);
        bf16x8 V3 = *(const bf16x8*)(vb + (size_t)ks * 128 + 96);
        // A-frags from swizzled LDS; m&7 == l16&7 (mt*16 = 0 mod 8)
        #pragma unroll
        for (int kf = 0; kf < 4; ++kf) {
            const int q2 = (kf * 4 + l4) * 2;
            const int p0 = (q2       ^ (l16 & 7)) * 4;
            const int p1 = ((q2 + 1) ^ (l16 & 7)) * 4;
            const bf16x8 Vk = kf == 0 ? V0 : kf == 1 ? V1 : kf == 2 ? V2 : V3;
            #pragma unroll
            for (int mt = 0; mt < 4; ++mt) {
                const int rowoff = (mt * 16 + l16) * 128;
                bf16x8 af = pack8(*(const float4*)&smem[cur][rowoff + p0],
                                  *(const float4*)&smem[cur][rowoff + p1]);
                acc[mt] = MFMA16(af, Vk, acc[mt]);
            }
        }
        __syncthreads();
    }
#undef STAGE

    // epilogue: out = relu(acc + Ux); D-frag: col=l16 -> e, row=l4*4+reg
    const size_t rowbase = (size_t)b * 2048 + m0;
    const int e = wv * 16 + l16;
    #pragma unroll
    for (int mt = 0; mt < 4; ++mt) {
        #pragma unroll
        for (int r = 0; r < 4; ++r) {
            const size_t row = rowbase + mt * 16 + l4 * 4 + r;
            const float v = acc[mt][r] + (float)Uxb[row * 128 + e];
            out[row * 128 + e] = v > 0.f ? v : 0.f;
        }
    }
}

// ---------------------------------------------------------------------------
extern "C" void kernel_launch(void* const* d_in, const int* in_sizes, int n_in,
                              void* d_out, int out_size, void* d_ws, size_t ws_size,
                              hipStream_t stream) {
    (void)in_sizes; (void)n_in; (void)out_size; (void)ws_size;
    const float* x    = (const float*)d_in[0];   // [8][2048][128]
    const float* mask = (const float*)d_in[1];   // [8][2048][2048]
    const float* Wu   = (const float*)d_in[2];   // [128][128]
    const float* bu   = (const float*)d_in[3];   // [128]
    const float* Wv   = (const float*)d_in[4];   // [128][128]
    const float* bv   = (const float*)d_in[5];   // [128]
    float* out        = (float*)d_out;           // [8][2048][128] f32

    __bf16* Vt  = (__bf16*)d_ws;                 // [8][128][2048] bf16 (4MB)
    __bf16* Uxb = Vt + (size_t)8 * 128 * 2048;   // [16384][128]  bf16 (4MB)

    hipLaunchKernelGGL(k1_uv, dim3(256), dim3(256), 0, stream, x, Wu, bu, Wv, bv, Uxb, Vt);
    hipLaunchKernelGGL(k2_agg, dim3(256), dim3(512), 0, stream, mask, Vt, Uxb, out);
}